// Round 10
// baseline (347.322 us; speedup 1.0000x reference)
//
#include <hip/hip_runtime.h>
#include <hip/hip_bf16.h>

// Difference3DCostVolume: cost[b,c,d,h,w] = l[b,c,h,w] - r[b,c,h,w-d] (w>=d), else 1.0
// Shapes: B=4, C=32, H=96, W=312, D=48. Output [B,C,D,H,W] f32 = 736 MB -> write-bound.
//
// R10 = R9 with the l-side moved from LDS to REGISTERS:
//  - each thread owns m4 slots {tid, tid+512, tid+1024, (tid+1536 if <1872)};
//    its 4 l-float4s are loaded once (coalesced) and reused for all 48 d's.
//  - LDS now holds only the r chunk (30208 B) -> 4 blocks/CU = 32 waves (2x MLP).
//  - d-shift at LDS-read: hi/lo ds_read_b128 + literal word-select per RR=d&3.
//  - per-slot w is fixed: w_k = 4*((tid+512k) % 78); predicate (w+j >= d).
//  - extents: 24 rows = 29952 B contiguous per (bc,qtr,d).

#define BB 4
#define CC 32
#define HH 96
#define WW 312
#define DD 48
#define CH 24                  // rows per block
#define NQ (HH / CH)           // 4
#define CHF (CH * WW)          // 7488 floats per chunk
#define CH4 (CHF / 4)          // 1872 float4 per chunk
#define NT 512
#define NBLOCKS (BB * CC * NQ) // 512
#define PAD4 16                // front pad (float4) for rs underflow reads
#define K3LIM (CH4 - 3 * NT)   // 336: threads with a 4th slot

typedef float float4a __attribute__((ext_vector_type(4)));

__global__ __launch_bounds__(NT, 8) void cost_volume_kernel(
    const float* __restrict__ l, const float* __restrict__ r,
    float* __restrict__ out) {
    const int blk = blockIdx.x;
    const int qtr = blk & 3;
    const int bc = blk >> 2;
    const int h0 = qtr * CH;
    const int tid = threadIdx.x;

    __shared__ float rsm[PAD4 * 4 + CHF];     // 30208 B (front pad + r chunk)
    float4a* rs4 = reinterpret_cast<float4a*>(rsm);   // data at rs4[PAD4 + i]

    const float4a* lsrc = reinterpret_cast<const float4a*>(
        l + ((size_t)bc * HH + h0) * WW);
    const float4a* rsrc = reinterpret_cast<const float4a*>(
        r + ((size_t)bc * HH + h0) * WW);

    // ---- stage r chunk (straight aligned copy, 24 rows).
    for (int i = tid; i < CH4; i += NT)
        rs4[PAD4 + i] = rsrc[i];

    // ---- hoist this thread's l data into registers (slot 3 guarded).
    const bool has3 = (tid < K3LIM);
    const float4a a0 = lsrc[tid];
    const float4a a1 = lsrc[tid + NT];
    const float4a a2 = lsrc[tid + 2 * NT];
    const float4a a3 = lsrc[has3 ? (tid + 3 * NT) : tid];  // dummy-safe

    // per-slot first-float column (fixed for the whole kernel)
    const int w0 = 4 * (tid % 78);
    const int w1 = 4 * ((tid + NT) % 78);
    const int w2 = 4 * ((tid + 2 * NT) % 78);
    const int w3 = 4 * ((tid + 3 * NT) % 78);

    __syncthreads();

    float* obase = out + ((size_t)bc * DD * HH + h0) * (size_t)WW;

    // slot body: item m4 = tid + K*NT, l-regs A, first col WK.
#define SLOT(K, A, WK, RR, SELX, SELY, SELZ, SELW)                           \
    {                                                                        \
        const int m4 = tid + (K) * NT;                                       \
        const int b4 = PAD4 + m4 - dq;                                       \
        const float4a hi = rs4[b4];                                          \
        const float4a lo = ((RR) == 0) ? hi : rs4[b4 - 1];                   \
        float4a v;                                                           \
        v.x = ((WK)     >= d) ? ((A).x - (SELX)) : 1.0f;                     \
        v.y = ((WK) + 1 >= d) ? ((A).y - (SELY)) : 1.0f;                     \
        v.z = ((WK) + 2 >= d) ? ((A).z - (SELZ)) : 1.0f;                     \
        v.w = ((WK) + 3 >= d) ? ((A).w - (SELW)) : 1.0f;                     \
        *reinterpret_cast<float4a*>(od + 4 * m4) = v;                        \
    }

#define RRBODY(RR, SELX, SELY, SELZ, SELW)                                   \
    {                                                                        \
        float* od = obase + (size_t)(RR) * (HH * WW);                        \
        for (int dq = 0; dq < 12; ++dq, od += (size_t)4 * HH * WW) {         \
            const int d = 4 * dq + (RR);                                     \
            SLOT(0, a0, w0, RR, SELX, SELY, SELZ, SELW)                      \
            SLOT(1, a1, w1, RR, SELX, SELY, SELZ, SELW)                      \
            SLOT(2, a2, w2, RR, SELX, SELY, SELZ, SELW)                      \
            if (has3) SLOT(3, a3, w3, RR, SELX, SELY, SELZ, SELW)            \
        }                                                                    \
    }

    RRBODY(0, hi.x, hi.y, hi.z, hi.w)
    RRBODY(1, lo.w, hi.x, hi.y, hi.z)
    RRBODY(2, lo.z, lo.w, hi.x, hi.y)
    RRBODY(3, lo.y, lo.z, lo.w, hi.x)
#undef RRBODY
#undef SLOT
}

extern "C" void kernel_launch(void* const* d_in, const int* in_sizes, int n_in,
                              void* d_out, int out_size, void* d_ws, size_t ws_size,
                              hipStream_t stream) {
    const float* l = (const float*)d_in[0];
    const float* r = (const float*)d_in[1];
    float* out = (float*)d_out;
    cost_volume_kernel<<<dim3(NBLOCKS), dim3(NT), 0, stream>>>(l, r, out);
}

// Round 11
// 154.039 us; speedup vs baseline: 2.2548x; 2.2548x over previous
//
#include <hip/hip_runtime.h>
#include <hip/hip_bf16.h>

// Difference3DCostVolume: cost[b,c,d,h,w] = l[b,c,h,w] - r[b,c,h,w-d] (w>=d), else 1.0
// Shapes: B=4, C=32, H=96, W=312, D=48. Output [B,C,D,H,W] f32 = 736 MB -> write-bound.
//
// R11 = R9 (150.8 us, verified) + ONE change: output stores are nontemporal
// (stream past L2; output is write-once never-read). Staging loads & LDS
// reads unchanged. R10's register-l variant spilled (launch_bounds 64-VGPR cap)
// and is reverted.
//
// Design (R9): block = (bc, h-quarter of 24 rows), 512 blocks x 512 thr,
// LDS 60KB -> 2 blocks/CU.
//  - stage l,r rows ONCE as straight aligned float4 copies (31 MB total reads).
//  - d-shift at LDS-read: two aligned ds_read_b128 (lo,hi) + literal word-select,
//    specialized over RR = d&3.
//  - emit all 48 d's per block: each extent = 24 rows = 29952 B contiguous.
//  - pad predicate from running w4 = m4 % 78 (step 44 = 512 mod 78).

#define BB 4
#define CC 32
#define HH 96
#define WW 312
#define DD 48
#define CH 24                  // rows per block
#define NQ (HH / CH)           // 4
#define CHF (CH * WW)          // 7488 floats per chunk
#define CH4 (CHF / 4)          // 1872 float4 per chunk
#define NT 512
#define NBLOCKS (BB * CC * NQ) // 512
#define PAD4 16                // front pad (float4) for rs underflow reads
#define W4STEP (NT % 78)       // 44

typedef float float4a __attribute__((ext_vector_type(4)));

__global__ __launch_bounds__(NT) void cost_volume_kernel(
    const float* __restrict__ l, const float* __restrict__ r,
    float* __restrict__ out) {
    const int blk = blockIdx.x;
    const int qtr = blk & 3;
    const int bc = blk >> 2;
    const int h0 = qtr * CH;
    const int tid = threadIdx.x;

    __shared__ float ls[CHF];                 // 29952 B
    __shared__ float rsm[PAD4 * 4 + CHF];     // 30208 B (front pad + data)

    float4a* ls4 = reinterpret_cast<float4a*>(ls);
    float4a* rs4 = reinterpret_cast<float4a*>(rsm);   // data at rs4[PAD4 + i]

    // ---- stage: straight contiguous copies (24 full rows each), all vec4.
    {
        const float4a* lsrc = reinterpret_cast<const float4a*>(
            l + ((size_t)bc * HH + h0) * WW);
        const float4a* rsrc = reinterpret_cast<const float4a*>(
            r + ((size_t)bc * HH + h0) * WW);
        for (int i = tid; i < CH4; i += NT) {
            ls4[i] = lsrc[i];
            rs4[PAD4 + i] = rsrc[i];
        }
    }
    __syncthreads();

    const int w40 = tid % 78;                 // w4 of this thread's first item
    float* obase = out + ((size_t)bc * DD * HH + h0) * (size_t)WW;

    // For d = 4*dq + RR: r window per lane j is chunk float 4*m4 + j - d ->
    //   lo = rs4[PAD4+m4-dq-1], hi = rs4[PAD4+m4-dq]; word select literal per RR.
#define RRBODY(RR, SELX, SELY, SELZ, SELW)                                   \
    {                                                                        \
        float* od = obase + (size_t)RR * (HH * WW);                          \
        for (int dq = 0; dq < 12; ++dq, od += (size_t)4 * HH * WW) {         \
            const int d = 4 * dq + RR;                                       \
            int w4 = w40;                                                    \
            for (int m4 = tid; m4 < CH4; m4 += NT) {                         \
                const float4a a = ls4[m4];                                   \
                const int b4 = PAD4 + m4 - dq;                               \
                const float4a hi = rs4[b4];                                  \
                const float4a lo = (RR == 0) ? hi : rs4[b4 - 1];             \
                const int w = 4 * w4;                                        \
                float4a v;                                                   \
                v.x = (w     >= d) ? (a.x - (SELX)) : 1.0f;                  \
                v.y = (w + 1 >= d) ? (a.y - (SELY)) : 1.0f;                  \
                v.z = (w + 2 >= d) ? (a.z - (SELZ)) : 1.0f;                  \
                v.w = (w + 3 >= d) ? (a.w - (SELW)) : 1.0f;                  \
                __builtin_nontemporal_store(                                 \
                    v, reinterpret_cast<float4a*>(od + 4 * m4));             \
                w4 += W4STEP;                                                \
                if (w4 >= 78) w4 -= 78;                                      \
            }                                                                \
        }                                                                    \
    }

    RRBODY(0, hi.x, hi.y, hi.z, hi.w)
    RRBODY(1, lo.w, hi.x, hi.y, hi.z)
    RRBODY(2, lo.z, lo.w, hi.x, hi.y)
    RRBODY(3, lo.y, lo.z, lo.w, hi.x)
#undef RRBODY
}

extern "C" void kernel_launch(void* const* d_in, const int* in_sizes, int n_in,
                              void* d_out, int out_size, void* d_ws, size_t ws_size,
                              hipStream_t stream) {
    const float* l = (const float*)d_in[0];
    const float* r = (const float*)d_in[1];
    float* out = (float*)d_out;
    cost_volume_kernel<<<dim3(NBLOCKS), dim3(NT), 0, stream>>>(l, r, out);
}

// Round 12
// 150.085 us; speedup vs baseline: 2.3142x; 1.0263x over previous
//
#include <hip/hip_runtime.h>
#include <hip/hip_bf16.h>

// Difference3DCostVolume: cost[b,c,d,h,w] = l[b,c,h,w] - r[b,c,h,w-d] (w>=d), else 1.0
// Shapes: B=4, C=32, H=96, W=312, D=48. Output [B,C,D,H,W] f32 = 736 MB -> write-bound.
//
// R12 = R9 (150.8 us; plain stores — R11's nt-store was a null) + ONE change:
// XCD-grouping block remap. The 4 qtr-blocks of each bc write adjacent 30 KB
// pieces of the same 117 KB d-slice in lockstep; mapping them to the SAME XCD
// (physical blk%8 fixed, ids 8 apart -> in pace) turns each XCD's L2->DRAM
// writeback stream into ~16 long contiguous-chunk streams instead of 64
// fragmented ones.
//
// Design (R9): block = (bc, h-quarter of 24 rows), 512 blocks x 512 thr,
// LDS 60KB -> 2 blocks/CU, single generation.
//  - stage l,r rows ONCE as straight aligned float4 copies (31 MB total reads).
//  - d-shift at LDS-read: two aligned ds_read_b128 (lo,hi) + literal word-select,
//    specialized over RR = d&3.
//  - emit all 48 d's per block: each extent = 24 rows = 29952 B contiguous.
//  - pad predicate from running w4 = m4 % 78 (step 44 = 512 mod 78).

#define BB 4
#define CC 32
#define HH 96
#define WW 312
#define DD 48
#define CH 24                  // rows per block
#define NQ (HH / CH)           // 4
#define CHF (CH * WW)          // 7488 floats per chunk
#define CH4 (CHF / 4)          // 1872 float4 per chunk
#define NT 512
#define NBLOCKS (BB * CC * NQ) // 512
#define PAD4 16                // front pad (float4) for rs underflow reads
#define W4STEP (NT % 78)       // 44

typedef float float4a __attribute__((ext_vector_type(4)));

__global__ __launch_bounds__(NT) void cost_volume_kernel(
    const float* __restrict__ l, const float* __restrict__ r,
    float* __restrict__ out) {
    // XCD-grouping remap: physical XCD = blk & 7 (dispatch round-robin).
    // Give each XCD 16 bc's; the 4 qtr-blocks of a bc sit 8 apart (same XCD,
    // launched back-to-back -> in pace, writing adjacent 30 KB extents).
    const int x = blockIdx.x & 7;
    const int j = blockIdx.x >> 3;            // 0..63
    const int bc = x * 16 + (j >> 2);         // 0..127 (bijective)
    const int qtr = j & 3;
    const int h0 = qtr * CH;
    const int tid = threadIdx.x;

    __shared__ float ls[CHF];                 // 29952 B
    __shared__ float rsm[PAD4 * 4 + CHF];     // 30208 B (front pad + data)

    float4a* ls4 = reinterpret_cast<float4a*>(ls);
    float4a* rs4 = reinterpret_cast<float4a*>(rsm);   // data at rs4[PAD4 + i]

    // ---- stage: straight contiguous copies (24 full rows each), all vec4.
    {
        const float4a* lsrc = reinterpret_cast<const float4a*>(
            l + ((size_t)bc * HH + h0) * WW);
        const float4a* rsrc = reinterpret_cast<const float4a*>(
            r + ((size_t)bc * HH + h0) * WW);
        for (int i = tid; i < CH4; i += NT) {
            ls4[i] = lsrc[i];
            rs4[PAD4 + i] = rsrc[i];
        }
    }
    __syncthreads();

    const int w40 = tid % 78;                 // w4 of this thread's first item
    float* obase = out + ((size_t)bc * DD * HH + h0) * (size_t)WW;

    // For d = 4*dq + RR: r window per lane j is chunk float 4*m4 + j - d ->
    //   lo = rs4[PAD4+m4-dq-1], hi = rs4[PAD4+m4-dq]; word select literal per RR.
#define RRBODY(RR, SELX, SELY, SELZ, SELW)                                   \
    {                                                                        \
        float* od = obase + (size_t)RR * (HH * WW);                          \
        for (int dq = 0; dq < 12; ++dq, od += (size_t)4 * HH * WW) {         \
            const int d = 4 * dq + RR;                                       \
            int w4 = w40;                                                    \
            for (int m4 = tid; m4 < CH4; m4 += NT) {                         \
                const float4a a = ls4[m4];                                   \
                const int b4 = PAD4 + m4 - dq;                               \
                const float4a hi = rs4[b4];                                  \
                const float4a lo = (RR == 0) ? hi : rs4[b4 - 1];             \
                const int w = 4 * w4;                                        \
                float4a v;                                                   \
                v.x = (w     >= d) ? (a.x - (SELX)) : 1.0f;                  \
                v.y = (w + 1 >= d) ? (a.y - (SELY)) : 1.0f;                  \
                v.z = (w + 2 >= d) ? (a.z - (SELZ)) : 1.0f;                  \
                v.w = (w + 3 >= d) ? (a.w - (SELW)) : 1.0f;                  \
                *reinterpret_cast<float4a*>(od + 4 * m4) = v;                \
                w4 += W4STEP;                                                \
                if (w4 >= 78) w4 -= 78;                                      \
            }                                                                \
        }                                                                    \
    }

    RRBODY(0, hi.x, hi.y, hi.z, hi.w)
    RRBODY(1, lo.w, hi.x, hi.y, hi.z)
    RRBODY(2, lo.z, lo.w, hi.x, hi.y)
    RRBODY(3, lo.y, lo.z, lo.w, hi.x)
#undef RRBODY
}

extern "C" void kernel_launch(void* const* d_in, const int* in_sizes, int n_in,
                              void* d_out, int out_size, void* d_ws, size_t ws_size,
                              hipStream_t stream) {
    const float* l = (const float*)d_in[0];
    const float* r = (const float*)d_in[1];
    float* out = (float*)d_out;
    cost_volume_kernel<<<dim3(NBLOCKS), dim3(NT), 0, stream>>>(l, r, out);
}

// Round 13
// 150.080 us; speedup vs baseline: 2.3142x; 1.0000x over previous
//
#include <hip/hip_runtime.h>
#include <hip/hip_bf16.h>

// Difference3DCostVolume: cost[b,c,d,h,w] = l[b,c,h,w] - r[b,c,h,w-d] (w>=d), else 1.0
// Shapes: B=4, C=32, H=96, W=312, D=48. Output [B,C,D,H,W] f32 = 736 MB -> write-bound.
//
// R13 = R9 inner loop (verified), two memory-side structural changes:
//  1) 1 block/CU: block = (bc, h-half of 48 rows); 256 blocks x 512 thr;
//     LDS 120 KB (ls 58.5 KB + rs 58.75 KB) -> 32 write streams/XCD (was 64),
//     extents 48 rows = 59904 B contiguous (was 29952).
//  2) d-monotonic extent order: dq outer, RR bodies inner -> each block writes
//     its 48 extents at monotonically increasing addresses (117 KB stride).
//  - stage l,r rows ONCE as straight aligned float4 copies (31 MB total reads).
//  - d-shift at LDS-read: two aligned ds_read_b128 (lo,hi) + literal word-select,
//    specialized over RR = d&3.
//  - pad predicate from running w4 = m4 % 78 (step 44 = 512 mod 78).

#define BB 4
#define CC 32
#define HH 96
#define WW 312
#define DD 48
#define CH 48                  // rows per block
#define NHALF (HH / CH)        // 2
#define CHF (CH * WW)          // 14976 floats per chunk
#define CH4 (CHF / 4)          // 3744 float4 per chunk
#define NT 512
#define NBLOCKS (BB * CC * NHALF) // 256
#define PAD4 16                // front pad (float4) >= max d/4 for rs underflow
#define W4STEP (NT % 78)       // 44

typedef float float4a __attribute__((ext_vector_type(4)));

__global__ __launch_bounds__(NT) void cost_volume_kernel(
    const float* __restrict__ l, const float* __restrict__ r,
    float* __restrict__ out) {
    const int blk = blockIdx.x;
    const int half = blk & 1;
    const int bc = blk >> 1;
    const int h0 = half * CH;
    const int tid = threadIdx.x;

    __shared__ float ls[CHF];                 // 59904 B
    __shared__ float rsm[PAD4 * 4 + CHF];     // 60160 B (front pad + data)

    float4a* ls4 = reinterpret_cast<float4a*>(ls);
    float4a* rs4 = reinterpret_cast<float4a*>(rsm);   // data at rs4[PAD4 + i]

    // ---- stage: straight contiguous copies (48 full rows each), all vec4.
    {
        const float4a* lsrc = reinterpret_cast<const float4a*>(
            l + ((size_t)bc * HH + h0) * WW);
        const float4a* rsrc = reinterpret_cast<const float4a*>(
            r + ((size_t)bc * HH + h0) * WW);
        for (int i = tid; i < CH4; i += NT) {
            ls4[i] = lsrc[i];
            rs4[PAD4 + i] = rsrc[i];
        }
    }
    __syncthreads();

    const int w40 = tid % 78;                 // w4 of this thread's first item
    float* obase = out + ((size_t)bc * DD * HH + h0) * (size_t)WW;

    // For d = 4*dq + RR: r window per lane j is chunk float 4*m4 + j - d ->
    //   lo = rs4[PAD4+m4-dq-1], hi = rs4[PAD4+m4-dq]; word select literal per RR.
    //   (b4 min = PAD4 - 11 = 5 > 0; first-row w<d lanes read garbage, pad-masked.)
#define BODY(RR, SELX, SELY, SELZ, SELW)                                     \
    {                                                                        \
        const int d = 4 * dq + (RR);                                         \
        float* od = obase + (size_t)d * (HH * WW);                           \
        int w4 = w40;                                                        \
        for (int m4 = tid; m4 < CH4; m4 += NT) {                             \
            const float4a a = ls4[m4];                                       \
            const int b4 = PAD4 + m4 - dq;                                   \
            const float4a hi = rs4[b4];                                      \
            const float4a lo = ((RR) == 0) ? hi : rs4[b4 - 1];               \
            const int w = 4 * w4;                                            \
            float4a v;                                                       \
            v.x = (w     >= d) ? (a.x - (SELX)) : 1.0f;                      \
            v.y = (w + 1 >= d) ? (a.y - (SELY)) : 1.0f;                      \
            v.z = (w + 2 >= d) ? (a.z - (SELZ)) : 1.0f;                      \
            v.w = (w + 3 >= d) ? (a.w - (SELW)) : 1.0f;                      \
            *reinterpret_cast<float4a*>(od + 4 * m4) = v;                    \
            w4 += W4STEP;                                                    \
            if (w4 >= 78) w4 -= 78;                                          \
        }                                                                    \
    }

    for (int dq = 0; dq < 12; ++dq) {         // d ascends 0,1,2,...,47
        BODY(0, hi.x, hi.y, hi.z, hi.w)
        BODY(1, lo.w, hi.x, hi.y, hi.z)
        BODY(2, lo.z, lo.w, hi.x, hi.y)
        BODY(3, lo.y, lo.z, lo.w, hi.x)
    }
#undef BODY
}

extern "C" void kernel_launch(void* const* d_in, const int* in_sizes, int n_in,
                              void* d_out, int out_size, void* d_ws, size_t ws_size,
                              hipStream_t stream) {
    const float* l = (const float*)d_in[0];
    const float* r = (const float*)d_in[1];
    float* out = (float*)d_out;
    cost_volume_kernel<<<dim3(NBLOCKS), dim3(NT), 0, stream>>>(l, r, out);
}